// Round 1
// baseline (269.174 us; speedup 1.0000x reference)
//
#include <hip/hip_runtime.h>
#include <math.h>

typedef unsigned short u16;
typedef __bf16 bf16x8 __attribute__((ext_vector_type(8)));
typedef float f32x4 __attribute__((ext_vector_type(4)));

#define EDIM 768
#define MTOT 8192   // B*T = 8*1024
#define NH   12
#define HD   64

__device__ __forceinline__ u16 f2bf(float f) {
    __bf16 h = (__bf16)f;
    return __builtin_bit_cast(u16, h);
}

// ---------------- fp32 -> bf16 convert (vectorized, 8 elems/thread) ----------
__global__ void cvt_kernel(const float* __restrict__ src, u16* __restrict__ dst, int n8) {
    int i = blockIdx.x * blockDim.x + threadIdx.x;
    if (i >= n8) return;
    const float4* s = reinterpret_cast<const float4*>(src) + 2 * (size_t)i;
    float4 v0 = s[0], v1 = s[1];
    union { u16 u[8]; uint4 v; } o;
    o.u[0] = f2bf(v0.x); o.u[1] = f2bf(v0.y); o.u[2] = f2bf(v0.z); o.u[3] = f2bf(v0.w);
    o.u[4] = f2bf(v1.x); o.u[5] = f2bf(v1.y); o.u[6] = f2bf(v1.z); o.u[7] = f2bf(v1.w);
    reinterpret_cast<uint4*>(dst)[i] = o.v;
}

// ---------------- GEMM y = A @ W^T + b  (A row-major [8192][768] bf16, W row-major [768][768] bf16)
// MODE 0: A=xb, mats 0,1,2 (q,k,v) -> scatter epilogues. MODE 1: A=ctx, mat 3 -> fp32 out.
template<int MODE>
__global__ __launch_bounds__(256) void gemm_bt(
    const u16* __restrict__ A, const u16* __restrict__ Wb,
    const float* __restrict__ bq, const float* __restrict__ bk,
    const float* __restrict__ bv, const float* __restrict__ bo,
    u16* __restrict__ qws, u16* __restrict__ kws, u16* __restrict__ vTws,
    float* __restrict__ out)
{
    __shared__ __align__(16) u16 As[128][40];   // 128 x (32 + 8 pad) bf16
    __shared__ __align__(16) u16 Bs[128][40];

    const int tid  = threadIdx.x;
    const int lane = tid & 63, wid = tid >> 6;
    const int g = lane >> 4, c = lane & 15;
    const int wm = wid >> 1, wn = wid & 1;            // 2x2 waves of 64x64
    const int bm0 = blockIdx.x * 128;
    int mat, nb;
    if (MODE == 0) { mat = blockIdx.y / 6; nb = blockIdx.y % 6; }
    else           { mat = 3;              nb = blockIdx.y; }
    const u16* W = Wb + (size_t)mat * EDIM * EDIM;
    const int bn0 = nb * 128;

    f32x4 acc[4][4];
    #pragma unroll
    for (int i = 0; i < 4; i++)
        #pragma unroll
        for (int j = 0; j < 4; j++) acc[i][j] = (f32x4){0.f, 0.f, 0.f, 0.f};

    for (int k0 = 0; k0 < EDIM; k0 += 32) {
        __syncthreads();
        #pragma unroll
        for (int rp = 0; rp < 2; ++rp) {
            int e = rp * 2048 + tid * 8;
            int row = e >> 5, col = e & 31;
            *reinterpret_cast<uint4*>(&As[row][col]) =
                *reinterpret_cast<const uint4*>(&A[(size_t)(bm0 + row) * EDIM + k0 + col]);
            *reinterpret_cast<uint4*>(&Bs[row][col]) =
                *reinterpret_cast<const uint4*>(&W[(size_t)(bn0 + row) * EDIM + k0 + col]);
        }
        __syncthreads();

        bf16x8 af[4], bfr[4];
        #pragma unroll
        for (int mi = 0; mi < 4; mi++)
            af[mi] = *reinterpret_cast<const bf16x8*>(&As[wm * 64 + mi * 16 + c][g * 8]);
        #pragma unroll
        for (int ni = 0; ni < 4; ni++)
            bfr[ni] = *reinterpret_cast<const bf16x8*>(&Bs[wn * 64 + ni * 16 + c][g * 8]);
        #pragma unroll
        for (int mi = 0; mi < 4; mi++)
            #pragma unroll
            for (int ni = 0; ni < 4; ni++)
                acc[mi][ni] = __builtin_amdgcn_mfma_f32_16x16x32_bf16(af[mi], bfr[ni], acc[mi][ni], 0, 0, 0);
    }

    // Epilogue. C/D layout: col n = c, row m = g*4 + r.
    #pragma unroll
    for (int mi = 0; mi < 4; mi++) {
        #pragma unroll
        for (int ni = 0; ni < 4; ni++) {
            const int n_in = bn0 + wn * 64 + ni * 16 + c;        // [0,768)
            const int m0w  = bm0 + wm * 64 + mi * 16 + g * 4;    // first of 4 rows
            if (MODE == 1) {
                const float bias = bo[n_in];
                #pragma unroll
                for (int r = 0; r < 4; r++)
                    out[(size_t)(m0w + r) * EDIM + n_in] = acc[mi][ni][r] + bias;
            } else {
                const int h = n_in >> 6, d = n_in & 63;
                const int b = m0w >> 10, t = m0w & 1023;
                if (mat == 0) {
                    const float bias = bq[n_in];
                    #pragma unroll
                    for (int r = 0; r < 4; r++)
                        qws[((size_t)(b * NH + h) * 1024 + (t + r)) * HD + d] =
                            f2bf((acc[mi][ni][r] + bias) * 0.125f);   // pre-scale by 1/sqrt(64)
                } else if (mat == 1) {
                    const float bias = bk[n_in];
                    #pragma unroll
                    for (int r = 0; r < 4; r++)
                        kws[((size_t)(b * NH + h) * 1024 + (t + r)) * HD + d] =
                            f2bf(acc[mi][ni][r] + bias);
                } else {
                    const float bias = bv[n_in];
                    ushort4 pk;
                    pk.x = f2bf(acc[mi][ni][0] + bias);
                    pk.y = f2bf(acc[mi][ni][1] + bias);
                    pk.z = f2bf(acc[mi][ni][2] + bias);
                    pk.w = f2bf(acc[mi][ni][3] + bias);
                    // v stored transposed: [B,H,D,T], 4 consecutive t -> 8B store
                    *reinterpret_cast<ushort4*>(&vTws[((size_t)(b * NH + h) * HD + d) * 1024 + t]) = pk;
                }
            }
        }
    }
}

// ---------------- causal flash attention, 64 q-rows/block, 4 waves x 16 rows --
__global__ __launch_bounds__(256) void attn_kernel(
    const u16* __restrict__ qws, const u16* __restrict__ kws,
    const u16* __restrict__ vTws, u16* __restrict__ ctx)
{
    __shared__ __align__(16) u16 Ks[64][72];      // [kv][d + 8 pad]
    __shared__ __align__(16) u16 Vs[64][72];      // [d][kv + 8 pad]
    __shared__ __align__(16) u16 Ps[4][16][72];   // per-wave P round-trip

    const int tid = threadIdx.x, lane = tid & 63, wid = tid >> 6;
    const int g = lane >> 4, c = lane & 15;
    const int bh = blockIdx.y;                 // 0..95
    const int q0 = blockIdx.x * 64;
    const u16* Qb = qws + (size_t)bh * 1024 * HD;
    const u16* Kb = kws + (size_t)bh * 1024 * HD;
    const u16* Vb = vTws + (size_t)bh * HD * 1024;

    // Q fragments (A layout: row = c, k = kk*32 + g*8 + j), resident whole kernel
    bf16x8 qf[2];
    const int qrow = q0 + wid * 16 + c;
    #pragma unroll
    for (int kk = 0; kk < 2; kk++)
        qf[kk] = *reinterpret_cast<const bf16x8*>(&Qb[(size_t)qrow * HD + kk * 32 + g * 8]);

    f32x4 o[4];
    #pragma unroll
    for (int df = 0; df < 4; df++) o[df] = (f32x4){0.f, 0.f, 0.f, 0.f};
    float m_run[4], l_run[4];
    #pragma unroll
    for (int r = 0; r < 4; r++) { m_run[r] = -INFINITY; l_run[r] = 0.f; }

    const int ntiles = (q0 >> 6) + 1;
    for (int it = 0; it < ntiles; ++it) {
        const int kv0 = it * 64;
        __syncthreads();
        #pragma unroll
        for (int rp = 0; rp < 2; ++rp) {
            int e = rp * 2048 + tid * 8;
            int row = e >> 6, col = e & 63;
            *reinterpret_cast<uint4*>(&Ks[row][col]) =
                *reinterpret_cast<const uint4*>(&Kb[(size_t)(kv0 + row) * HD + col]);
            *reinterpret_cast<uint4*>(&Vs[row][col]) =
                *reinterpret_cast<const uint4*>(&Vb[(size_t)row * 1024 + kv0 + col]);
        }
        __syncthreads();

        // S = Q K^T  (pre-scaled)
        float s[4][4];
        #pragma unroll
        for (int cf = 0; cf < 4; cf++) {
            f32x4 sc = (f32x4){0.f, 0.f, 0.f, 0.f};
            #pragma unroll
            for (int kk = 0; kk < 2; kk++) {
                bf16x8 kb = *reinterpret_cast<const bf16x8*>(&Ks[cf * 16 + c][kk * 32 + g * 8]);
                sc = __builtin_amdgcn_mfma_f32_16x16x32_bf16(qf[kk], kb, sc, 0, 0, 0);
            }
            #pragma unroll
            for (int r = 0; r < 4; r++) s[cf][r] = sc[r];
        }
        if (kv0 == q0) {   // diagonal tile: causal mask
            #pragma unroll
            for (int cf = 0; cf < 4; cf++) {
                const int kv = kv0 + cf * 16 + c;
                #pragma unroll
                for (int r = 0; r < 4; r++) {
                    const int q = q0 + wid * 16 + g * 4 + r;
                    if (kv > q) s[cf][r] = -INFINITY;
                }
            }
        }
        // online softmax (rows live across 16-lane group)
        #pragma unroll
        for (int r = 0; r < 4; r++) {
            float tm = fmaxf(fmaxf(s[0][r], s[1][r]), fmaxf(s[2][r], s[3][r]));
            tm = fmaxf(tm, __shfl_xor(tm, 1));
            tm = fmaxf(tm, __shfl_xor(tm, 2));
            tm = fmaxf(tm, __shfl_xor(tm, 4));
            tm = fmaxf(tm, __shfl_xor(tm, 8));
            const float mn = fmaxf(m_run[r], tm);
            const float corr = __expf(m_run[r] - mn);
            float rs = 0.f;
            #pragma unroll
            for (int cf = 0; cf < 4; cf++) {
                const float p = __expf(s[cf][r] - mn);
                s[cf][r] = p;
                rs += p;
            }
            rs += __shfl_xor(rs, 1); rs += __shfl_xor(rs, 2);
            rs += __shfl_xor(rs, 4); rs += __shfl_xor(rs, 8);
            l_run[r] = l_run[r] * corr + rs;
            m_run[r] = mn;
            #pragma unroll
            for (int df = 0; df < 4; df++) o[df][r] *= corr;
        }
        // P (C/D layout) -> LDS -> A-fragment layout
        #pragma unroll
        for (int r = 0; r < 4; r++)
            #pragma unroll
            for (int cf = 0; cf < 4; cf++)
                Ps[wid][g * 4 + r][cf * 16 + c] = f2bf(s[cf][r]);
        asm volatile("s_waitcnt lgkmcnt(0)" ::: "memory");
        __builtin_amdgcn_sched_barrier(0);
        bf16x8 pa[2];
        #pragma unroll
        for (int kk = 0; kk < 2; kk++)
            pa[kk] = *reinterpret_cast<const bf16x8*>(&Ps[wid][c][kk * 32 + g * 8]);
        // O += P @ V
        #pragma unroll
        for (int df = 0; df < 4; df++) {
            #pragma unroll
            for (int kk = 0; kk < 2; kk++) {
                bf16x8 vb = *reinterpret_cast<const bf16x8*>(&Vs[df * 16 + c][kk * 32 + g * 8]);
                o[df] = __builtin_amdgcn_mfma_f32_16x16x32_bf16(pa[kk], vb, o[df], 0, 0, 0);
            }
        }
    }

    // epilogue: ctx [B,T,E] bf16
    const int b = bh / NH, h = bh % NH;
    #pragma unroll
    for (int df = 0; df < 4; df++) {
        #pragma unroll
        for (int r = 0; r < 4; r++) {
            const float val = o[df][r] / l_run[r];
            const int t = q0 + wid * 16 + g * 4 + r;
            ctx[((size_t)(b * 1024 + t)) * EDIM + h * HD + df * 16 + c] = f2bf(val);
        }
    }
}

extern "C" void kernel_launch(void* const* d_in, const int* in_sizes, int n_in,
                              void* d_out, int out_size, void* d_ws, size_t ws_size,
                              hipStream_t stream) {
    const float* x  = (const float*)d_in[0];
    const float* Wq = (const float*)d_in[1];
    const float* bq = (const float*)d_in[2];
    const float* Wk = (const float*)d_in[3];
    const float* bk = (const float*)d_in[4];
    const float* Wv = (const float*)d_in[5];
    const float* bv = (const float*)d_in[6];
    const float* Wo = (const float*)d_in[7];
    const float* bo = (const float*)d_in[8];
    float* out = (float*)d_out;

    // workspace layout (all bf16 u16), total ~64.5 MB
    u16* xb  = (u16*)d_ws;
    u16* wb  = xb  + (size_t)MTOT * EDIM;          // 4 x [768][768]
    u16* qws = wb  + (size_t)4 * EDIM * EDIM;      // [B,H,T,D]
    u16* kws = qws + (size_t)MTOT * EDIM;          // [B,H,T,D]
    u16* vT  = kws + (size_t)MTOT * EDIM;          // [B,H,D,T]
    u16* ctx = vT  + (size_t)MTOT * EDIM;          // [B,T,E]

    cvt_kernel<<<(MTOT * EDIM / 8 + 255) / 256, 256, 0, stream>>>(x, xb, MTOT * EDIM / 8);
    const int wn8 = EDIM * EDIM / 8;
    cvt_kernel<<<(wn8 + 255) / 256, 256, 0, stream>>>(Wq, wb + 0 * (size_t)EDIM * EDIM, wn8);
    cvt_kernel<<<(wn8 + 255) / 256, 256, 0, stream>>>(Wk, wb + 1 * (size_t)EDIM * EDIM, wn8);
    cvt_kernel<<<(wn8 + 255) / 256, 256, 0, stream>>>(Wv, wb + 2 * (size_t)EDIM * EDIM, wn8);
    cvt_kernel<<<(wn8 + 255) / 256, 256, 0, stream>>>(Wo, wb + 3 * (size_t)EDIM * EDIM, wn8);

    gemm_bt<0><<<dim3(MTOT / 128, 18), 256, 0, stream>>>(xb, wb, bq, bk, bv, bo, qws, kws, vT, nullptr);
    attn_kernel<<<dim3(16, 96), 256, 0, stream>>>(qws, kws, vT, ctx);
    gemm_bt<1><<<dim3(MTOT / 128, 6), 256, 0, stream>>>(ctx, wb, bq, bk, bv, bo, nullptr, nullptr, nullptr, out);
}

// Round 4
// 204.790 us; speedup vs baseline: 1.3144x; 1.3144x over previous
//
#include <hip/hip_runtime.h>
#include <math.h>

typedef unsigned short u16;
typedef __bf16 bf16x8 __attribute__((ext_vector_type(8)));
typedef float f32x4 __attribute__((ext_vector_type(4)));

#define EDIM 768
#define MTOT 8192   // B*T = 8*1024
#define NH   12
#define HD   64

__device__ __forceinline__ u16 f2bf(float f) {
    __bf16 h = (__bf16)f;
    return __builtin_bit_cast(u16, h);
}

// ---------------- fp32 -> bf16 convert (vectorized, 8 elems/thread) ----------
__global__ void cvt_kernel(const float* __restrict__ src, u16* __restrict__ dst, int n8) {
    int i = blockIdx.x * blockDim.x + threadIdx.x;
    if (i >= n8) return;
    const float4* s = reinterpret_cast<const float4*>(src) + 2 * (size_t)i;
    float4 v0 = s[0], v1 = s[1];
    union { u16 u[8]; uint4 v; } o;
    o.u[0] = f2bf(v0.x); o.u[1] = f2bf(v0.y); o.u[2] = f2bf(v0.z); o.u[3] = f2bf(v0.w);
    o.u[4] = f2bf(v1.x); o.u[5] = f2bf(v1.y); o.u[6] = f2bf(v1.z); o.u[7] = f2bf(v1.w);
    reinterpret_cast<uint4*>(dst)[i] = o.v;
}

// all 4 weight matrices in one launch: grid.y selects the matrix
__global__ void cvt4_kernel(const float* __restrict__ s0, const float* __restrict__ s1,
                            const float* __restrict__ s2, const float* __restrict__ s3,
                            u16* __restrict__ dst) {
    int i = blockIdx.x * blockDim.x + threadIdx.x;       // 0..73727
    const int m = blockIdx.y;
    const float* src = (m == 0) ? s0 : (m == 1) ? s1 : (m == 2) ? s2 : s3;
    const float4* s = reinterpret_cast<const float4*>(src) + 2 * (size_t)i;
    float4 v0 = s[0], v1 = s[1];
    union { u16 u[8]; uint4 v; } o;
    o.u[0] = f2bf(v0.x); o.u[1] = f2bf(v0.y); o.u[2] = f2bf(v0.z); o.u[3] = f2bf(v0.w);
    o.u[4] = f2bf(v1.x); o.u[5] = f2bf(v1.y); o.u[6] = f2bf(v1.z); o.u[7] = f2bf(v1.w);
    reinterpret_cast<uint4*>(dst + (size_t)m * EDIM * EDIM)[i] = o.v;
}

// ---------------- GEMM y = A @ W^T + b  (A row-major [8192][768] bf16, W row-major [768][768] bf16)
// MODE 0: A=xb, mats 0,1,2 (q,k,v) -> scatter epilogues. MODE 1: A=ctx, mat 3 -> fp32 out.
template<int MODE>
__global__ __launch_bounds__(256) void gemm_bt(
    const u16* __restrict__ A, const u16* __restrict__ Wb,
    const float* __restrict__ bq, const float* __restrict__ bk,
    const float* __restrict__ bv, const float* __restrict__ bo,
    u16* __restrict__ qws, u16* __restrict__ kws, u16* __restrict__ vTws,
    float* __restrict__ out)
{
    __shared__ __align__(16) u16 As[128][40];   // 128 x (32 + 8 pad) bf16
    __shared__ __align__(16) u16 Bs[128][40];

    const int tid  = threadIdx.x;
    const int lane = tid & 63, wid = tid >> 6;
    const int g = lane >> 4, c = lane & 15;
    const int wm = wid >> 1, wn = wid & 1;            // 2x2 waves of 64x64
    const int bm0 = blockIdx.x * 128;
    int mat, nb;
    if (MODE == 0) { mat = blockIdx.y / 6; nb = blockIdx.y % 6; }
    else           { mat = 3;              nb = blockIdx.y; }
    const u16* W = Wb + (size_t)mat * EDIM * EDIM;
    const int bn0 = nb * 128;

    f32x4 acc[4][4];
    #pragma unroll
    for (int i = 0; i < 4; i++)
        #pragma unroll
        for (int j = 0; j < 4; j++) acc[i][j] = (f32x4){0.f, 0.f, 0.f, 0.f};

    for (int k0 = 0; k0 < EDIM; k0 += 32) {
        __syncthreads();
        #pragma unroll
        for (int rp = 0; rp < 2; ++rp) {
            int e = rp * 2048 + tid * 8;
            int row = e >> 5, col = e & 31;
            *reinterpret_cast<uint4*>(&As[row][col]) =
                *reinterpret_cast<const uint4*>(&A[(size_t)(bm0 + row) * EDIM + k0 + col]);
            *reinterpret_cast<uint4*>(&Bs[row][col]) =
                *reinterpret_cast<const uint4*>(&W[(size_t)(bn0 + row) * EDIM + k0 + col]);
        }
        __syncthreads();

        bf16x8 af[4], bfr[4];
        #pragma unroll
        for (int mi = 0; mi < 4; mi++)
            af[mi] = *reinterpret_cast<const bf16x8*>(&As[wm * 64 + mi * 16 + c][g * 8]);
        #pragma unroll
        for (int ni = 0; ni < 4; ni++)
            bfr[ni] = *reinterpret_cast<const bf16x8*>(&Bs[wn * 64 + ni * 16 + c][g * 8]);
        #pragma unroll
        for (int mi = 0; mi < 4; mi++)
            #pragma unroll
            for (int ni = 0; ni < 4; ni++)
                acc[mi][ni] = __builtin_amdgcn_mfma_f32_16x16x32_bf16(af[mi], bfr[ni], acc[mi][ni], 0, 0, 0);
    }

    // Epilogue. C/D layout: col n = c, row m = g*4 + r.
    #pragma unroll
    for (int mi = 0; mi < 4; mi++) {
        #pragma unroll
        for (int ni = 0; ni < 4; ni++) {
            const int n_in = bn0 + wn * 64 + ni * 16 + c;        // [0,768)
            const int m0w  = bm0 + wm * 64 + mi * 16 + g * 4;    // first of 4 rows
            if (MODE == 1) {
                const float bias = bo[n_in];
                #pragma unroll
                for (int r = 0; r < 4; r++)
                    out[(size_t)(m0w + r) * EDIM + n_in] = acc[mi][ni][r] + bias;
            } else {
                const int h = n_in >> 6, d = n_in & 63;
                const int b = m0w >> 10, t = m0w & 1023;
                if (mat == 0) {
                    const float bias = bq[n_in];
                    // pre-scale by log2(e)/sqrt(64) so attn works in exp2 domain
                    #pragma unroll
                    for (int r = 0; r < 4; r++)
                        qws[((size_t)(b * NH + h) * 1024 + (t + r)) * HD + d] =
                            f2bf((acc[mi][ni][r] + bias) * 0.180336880f);
                } else if (mat == 1) {
                    const float bias = bk[n_in];
                    #pragma unroll
                    for (int r = 0; r < 4; r++)
                        kws[((size_t)(b * NH + h) * 1024 + (t + r)) * HD + d] =
                            f2bf(acc[mi][ni][r] + bias);
                } else {
                    const float bias = bv[n_in];
                    ushort4 pk;
                    pk.x = f2bf(acc[mi][ni][0] + bias);
                    pk.y = f2bf(acc[mi][ni][1] + bias);
                    pk.z = f2bf(acc[mi][ni][2] + bias);
                    pk.w = f2bf(acc[mi][ni][3] + bias);
                    // v stored transposed: [B,H,D,T], 4 consecutive t -> 8B store
                    *reinterpret_cast<ushort4*>(&vTws[((size_t)(b * NH + h) * HD + d) * 1024 + t]) = pk;
                }
            }
        }
    }
}

// ---------------- causal flash attention, 64 q-rows/block, 4 waves x 16 rows --
// Swapped QK^T: S^T = mfma(K, Q) so each lane owns one q-row (q = lane&15) and
// softmax reductions are in-lane + 2 cross-group shfl.
__global__ __launch_bounds__(256) void attn_kernel(
    const u16* __restrict__ qws, const u16* __restrict__ kws,
    const u16* __restrict__ vTws, u16* __restrict__ ctx)
{
    __shared__ __align__(16) u16 Ks[64][72];      // [kv][d + 8 pad]
    __shared__ __align__(16) u16 Vs[64][72];      // [d][kv + 8 pad]
    __shared__ __align__(16) u16 Ps[4][16][72];   // per-wave P^T: [q][kv + 8 pad]

    const int tid = threadIdx.x, lane = tid & 63, wid = tid >> 6;
    const int g = lane >> 4, c = lane & 15;
    const int bh = blockIdx.x;                 // 0..95
    const int qb = 15 - blockIdx.y;            // longest blocks dispatched first
    const int q0 = qb * 64;
    const u16* Qb = qws + (size_t)bh * 1024 * HD;
    const u16* Kb = kws + (size_t)bh * 1024 * HD;
    const u16* Vb = vTws + (size_t)bh * HD * 1024;

    // Q fragment (B-operand layout: col = c (q), k = kk*32 + g*8 + j)
    bf16x8 qf[2];
    const int qrow = q0 + wid * 16 + c;
    #pragma unroll
    for (int kk = 0; kk < 2; kk++)
        qf[kk] = *reinterpret_cast<const bf16x8*>(&Qb[(size_t)qrow * HD + kk * 32 + g * 8]);

    f32x4 o[4];
    #pragma unroll
    for (int df = 0; df < 4; df++) o[df] = (f32x4){0.f, 0.f, 0.f, 0.f};
    float m_run = -INFINITY, l_run = 0.f;

    const int ntiles = qb + 1;
    for (int it = 0; it < ntiles; ++it) {
        const int kv0 = it * 64;
        __syncthreads();
        #pragma unroll
        for (int rp = 0; rp < 2; ++rp) {
            int e = rp * 2048 + tid * 8;
            int row = e >> 6, col = e & 63;
            *reinterpret_cast<uint4*>(&Ks[row][col]) =
                *reinterpret_cast<const uint4*>(&Kb[(size_t)(kv0 + row) * HD + col]);
            *reinterpret_cast<uint4*>(&Vs[row][col]) =
                *reinterpret_cast<const uint4*>(&Vb[(size_t)row * 1024 + kv0 + col]);
        }
        __syncthreads();

        // S^T = K Q^T; output col = c = q, row = kv = cf*16 + g*4 + r
        float st[4][4];
        __builtin_amdgcn_s_setprio(1);
        #pragma unroll
        for (int cf = 0; cf < 4; cf++) {
            f32x4 sc = (f32x4){0.f, 0.f, 0.f, 0.f};
            #pragma unroll
            for (int kk = 0; kk < 2; kk++) {
                bf16x8 kb = *reinterpret_cast<const bf16x8*>(&Ks[cf * 16 + c][kk * 32 + g * 8]);
                sc = __builtin_amdgcn_mfma_f32_16x16x32_bf16(kb, qf[kk], sc, 0, 0, 0);
            }
            #pragma unroll
            for (int r = 0; r < 4; r++) st[cf][r] = sc[r];
        }
        __builtin_amdgcn_s_setprio(0);

        if (kv0 == q0) {   // diagonal tile: causal mask (local indices)
            const int q = wid * 16 + c;
            #pragma unroll
            for (int cf = 0; cf < 4; cf++)
                #pragma unroll
                for (int r = 0; r < 4; r++)
                    if (cf * 16 + g * 4 + r > q) st[cf][r] = -INFINITY;
        }

        // online softmax: lane owns q-row = c; in-lane reduce 16 + 2 shfl over g
        float tm = st[0][0];
        #pragma unroll
        for (int cf = 0; cf < 4; cf++)
            #pragma unroll
            for (int r = 0; r < 4; r++) tm = fmaxf(tm, st[cf][r]);
        tm = fmaxf(tm, __shfl_xor(tm, 16));
        tm = fmaxf(tm, __shfl_xor(tm, 32));
        const float mn = fmaxf(m_run, tm);
        const float corr = exp2f(m_run - mn);
        float rs = 0.f;
        #pragma unroll
        for (int cf = 0; cf < 4; cf++)
            #pragma unroll
            for (int r = 0; r < 4; r++) {
                const float p = exp2f(st[cf][r] - mn);
                st[cf][r] = p;
                rs += p;
            }
        rs += __shfl_xor(rs, 16);
        rs += __shfl_xor(rs, 32);
        l_run = l_run * corr + rs;
        m_run = mn;

        // O rows are q = g*4 + r -> fetch corr from lane (g*4+r)
        #pragma unroll
        for (int r = 0; r < 4; r++) {
            const float cr = __shfl(corr, g * 4 + r);
            #pragma unroll
            for (int df = 0; df < 4; df++) o[df][r] *= cr;
        }

        // pack P^T -> per-wave LDS in PV A-fragment order: Ps[q][kv]
        #pragma unroll
        for (int cf = 0; cf < 4; cf++) {
            ushort4 pk;
            pk.x = f2bf(st[cf][0]); pk.y = f2bf(st[cf][1]);
            pk.z = f2bf(st[cf][2]); pk.w = f2bf(st[cf][3]);
            *reinterpret_cast<ushort4*>(&Ps[wid][c][cf * 16 + g * 4]) = pk;
        }
        asm volatile("s_waitcnt lgkmcnt(0)" ::: "memory");
        __builtin_amdgcn_sched_barrier(0);
        bf16x8 pa[2];
        #pragma unroll
        for (int kk = 0; kk < 2; kk++)
            pa[kk] = *reinterpret_cast<const bf16x8*>(&Ps[wid][c][kk * 32 + g * 8]);

        // O += P @ V
        __builtin_amdgcn_s_setprio(1);
        #pragma unroll
        for (int df = 0; df < 4; df++) {
            #pragma unroll
            for (int kk = 0; kk < 2; kk++) {
                bf16x8 vb = *reinterpret_cast<const bf16x8*>(&Vs[df * 16 + c][kk * 32 + g * 8]);
                o[df] = __builtin_amdgcn_mfma_f32_16x16x32_bf16(pa[kk], vb, o[df], 0, 0, 0);
            }
        }
        __builtin_amdgcn_s_setprio(0);
    }

    // epilogue: ctx [B,T,E] bf16; l for row q=g*4+r lives in lane (g*4+r)
    const int b = bh / NH, h = bh % NH;
    float lb[4];
    #pragma unroll
    for (int r = 0; r < 4; r++) lb[r] = __shfl(l_run, g * 4 + r);
    #pragma unroll
    for (int df = 0; df < 4; df++) {
        #pragma unroll
        for (int r = 0; r < 4; r++) {
            const float val = o[df][r] / lb[r];
            const int t = q0 + wid * 16 + g * 4 + r;
            ctx[((size_t)(b * 1024 + t)) * EDIM + h * HD + df * 16 + c] = f2bf(val);
        }
    }
}

extern "C" void kernel_launch(void* const* d_in, const int* in_sizes, int n_in,
                              void* d_out, int out_size, void* d_ws, size_t ws_size,
                              hipStream_t stream) {
    const float* x  = (const float*)d_in[0];
    const float* Wq = (const float*)d_in[1];
    const float* bq = (const float*)d_in[2];
    const float* Wk = (const float*)d_in[3];
    const float* bk = (const float*)d_in[4];
    const float* Wv = (const float*)d_in[5];
    const float* bv = (const float*)d_in[6];
    const float* Wo = (const float*)d_in[7];
    const float* bo = (const float*)d_in[8];
    float* out = (float*)d_out;

    // workspace layout (all bf16 u16), total ~64.5 MB
    u16* xb  = (u16*)d_ws;
    u16* wb  = xb  + (size_t)MTOT * EDIM;          // 4 x [768][768]
    u16* qws = wb  + (size_t)4 * EDIM * EDIM;      // [B,H,T,D]
    u16* kws = qws + (size_t)MTOT * EDIM;          // [B,H,T,D]
    u16* vT  = kws + (size_t)MTOT * EDIM;          // [B,H,D,T]
    u16* ctx = vT  + (size_t)MTOT * EDIM;          // [B,T,E]

    cvt_kernel<<<(MTOT * EDIM / 8 + 255) / 256, 256, 0, stream>>>(x, xb, MTOT * EDIM / 8);
    cvt4_kernel<<<dim3(EDIM * EDIM / 8 / 256, 4), 256, 0, stream>>>(Wq, Wk, Wv, Wo, wb);

    gemm_bt<0><<<dim3(MTOT / 128, 18), 256, 0, stream>>>(xb, wb, bq, bk, bv, bo, qws, kws, vT, nullptr);
    attn_kernel<<<dim3(96, 16), 256, 0, stream>>>(qws, kws, vT, ctx);
    gemm_bt<1><<<dim3(MTOT / 128, 6), 256, 0, stream>>>(ctx, wb, bq, bk, bv, bo, nullptr, nullptr, nullptr, out);
}

// Round 5
// 197.104 us; speedup vs baseline: 1.3656x; 1.0390x over previous
//
#include <hip/hip_runtime.h>
#include <math.h>

typedef unsigned short u16;
typedef __bf16 bf16x8 __attribute__((ext_vector_type(8)));
typedef float f32x4 __attribute__((ext_vector_type(4)));

#define EDIM 768
#define MTOT 8192   // B*T = 8*1024
#define NH   12
#define HD   64

__device__ __forceinline__ u16 f2bf(float f) {
    __bf16 h = (__bf16)f;
    return __builtin_bit_cast(u16, h);
}

// async global->LDS, 16 B per lane; LDS dest is wave-uniform base + lane*16
__device__ __forceinline__ void gld_lds16(const u16* g, u16* l) {
    __builtin_amdgcn_global_load_lds(
        (const __attribute__((address_space(1))) void*)g,
        (__attribute__((address_space(3))) void*)l,
        16, 0, 0);
}

// ---------------- fp32 -> bf16 convert (vectorized, 8 elems/thread) ----------
__global__ void cvt_kernel(const float* __restrict__ src, u16* __restrict__ dst, int n8) {
    int i = blockIdx.x * blockDim.x + threadIdx.x;
    if (i >= n8) return;
    const float4* s = reinterpret_cast<const float4*>(src) + 2 * (size_t)i;
    float4 v0 = s[0], v1 = s[1];
    union { u16 u[8]; uint4 v; } o;
    o.u[0] = f2bf(v0.x); o.u[1] = f2bf(v0.y); o.u[2] = f2bf(v0.z); o.u[3] = f2bf(v0.w);
    o.u[4] = f2bf(v1.x); o.u[5] = f2bf(v1.y); o.u[6] = f2bf(v1.z); o.u[7] = f2bf(v1.w);
    reinterpret_cast<uint4*>(dst)[i] = o.v;
}

// all 4 weight matrices in one launch: grid.y selects the matrix
__global__ void cvt4_kernel(const float* __restrict__ s0, const float* __restrict__ s1,
                            const float* __restrict__ s2, const float* __restrict__ s3,
                            u16* __restrict__ dst) {
    int i = blockIdx.x * blockDim.x + threadIdx.x;       // 0..73727
    const int m = blockIdx.y;
    const float* src = (m == 0) ? s0 : (m == 1) ? s1 : (m == 2) ? s2 : s3;
    const float4* s = reinterpret_cast<const float4*>(src) + 2 * (size_t)i;
    float4 v0 = s[0], v1 = s[1];
    union { u16 u[8]; uint4 v; } o;
    o.u[0] = f2bf(v0.x); o.u[1] = f2bf(v0.y); o.u[2] = f2bf(v0.z); o.u[3] = f2bf(v0.w);
    o.u[4] = f2bf(v1.x); o.u[5] = f2bf(v1.y); o.u[6] = f2bf(v1.z); o.u[7] = f2bf(v1.w);
    reinterpret_cast<uint4*>(dst + (size_t)m * EDIM * EDIM)[i] = o.v;
}

// ---------------- GEMM y = A @ W^T + b  (A row-major [8192][768] bf16, W row-major [768][768] bf16)
// m97 structure: global_load_lds width=16 staging into LINEAR LDS [128][32].
// MODE 0: A=xb, mats 0,1,2 (q,k,v) -> scatter epilogues. MODE 1: A=ctx, mat 3 -> fp32 out.
template<int MODE>
__global__ __launch_bounds__(256) void gemm_bt(
    const u16* __restrict__ A, const u16* __restrict__ Wb,
    const float* __restrict__ bq, const float* __restrict__ bk,
    const float* __restrict__ bv, const float* __restrict__ bo,
    u16* __restrict__ qws, u16* __restrict__ kws, u16* __restrict__ vTws,
    float* __restrict__ out)
{
    __shared__ __align__(16) u16 As[128][32];   // linear: global_load_lds dest
    __shared__ __align__(16) u16 Bs[128][32];

    const int tid  = threadIdx.x;
    const int lane = tid & 63, wid = tid >> 6;
    const int g = lane >> 4, c = lane & 15;
    const int wm = wid >> 1, wn = wid & 1;            // 2x2 waves of 64x64
    const int bm0 = blockIdx.x * 128;
    int mat, nb;
    if (MODE == 0) { mat = blockIdx.y / 6; nb = blockIdx.y % 6; }
    else           { mat = 3;              nb = blockIdx.y; }
    const u16* W = Wb + (size_t)mat * EDIM * EDIM;
    const int bn0 = nb * 128;

    // staging coords: lane l of wave wid covers row rp*64 + wid*16 + (l>>2), col (l&3)*8
    const int srow = wid * 16 + (lane >> 2);
    const int scol = (lane & 3) * 8;

    f32x4 acc[4][4];
    #pragma unroll
    for (int i = 0; i < 4; i++)
        #pragma unroll
        for (int j = 0; j < 4; j++) acc[i][j] = (f32x4){0.f, 0.f, 0.f, 0.f};

    for (int k0 = 0; k0 < EDIM; k0 += 32) {
        __syncthreads();
        #pragma unroll
        for (int rp = 0; rp < 2; ++rp) {
            gld_lds16(&A[(size_t)(bm0 + rp * 64 + srow) * EDIM + k0 + scol],
                      &As[rp * 64 + wid * 16][0]);
            gld_lds16(&W[(size_t)(bn0 + rp * 64 + srow) * EDIM + k0 + scol],
                      &Bs[rp * 64 + wid * 16][0]);
        }
        __syncthreads();

        bf16x8 af[4], bfr[4];
        #pragma unroll
        for (int mi = 0; mi < 4; mi++)
            af[mi] = *reinterpret_cast<const bf16x8*>(&As[wm * 64 + mi * 16 + c][g * 8]);
        #pragma unroll
        for (int ni = 0; ni < 4; ni++)
            bfr[ni] = *reinterpret_cast<const bf16x8*>(&Bs[wn * 64 + ni * 16 + c][g * 8]);
        #pragma unroll
        for (int mi = 0; mi < 4; mi++)
            #pragma unroll
            for (int ni = 0; ni < 4; ni++)
                acc[mi][ni] = __builtin_amdgcn_mfma_f32_16x16x32_bf16(af[mi], bfr[ni], acc[mi][ni], 0, 0, 0);
    }

    // Epilogue. C/D layout: col n = c, row m = g*4 + r.
    #pragma unroll
    for (int mi = 0; mi < 4; mi++) {
        #pragma unroll
        for (int ni = 0; ni < 4; ni++) {
            const int n_in = bn0 + wn * 64 + ni * 16 + c;        // [0,768)
            const int m0w  = bm0 + wm * 64 + mi * 16 + g * 4;    // first of 4 rows
            if (MODE == 1) {
                const float bias = bo[n_in];
                #pragma unroll
                for (int r = 0; r < 4; r++)
                    out[(size_t)(m0w + r) * EDIM + n_in] = acc[mi][ni][r] + bias;
            } else {
                const int h = n_in >> 6, d = n_in & 63;
                const int b = m0w >> 10, t = m0w & 1023;
                if (mat == 0) {
                    const float bias = bq[n_in];
                    // pre-scale by log2(e)/sqrt(64) so attn works in exp2 domain
                    #pragma unroll
                    for (int r = 0; r < 4; r++)
                        qws[((size_t)(b * NH + h) * 1024 + (t + r)) * HD + d] =
                            f2bf((acc[mi][ni][r] + bias) * 0.180336880f);
                } else if (mat == 1) {
                    const float bias = bk[n_in];
                    #pragma unroll
                    for (int r = 0; r < 4; r++)
                        kws[((size_t)(b * NH + h) * 1024 + (t + r)) * HD + d] =
                            f2bf(acc[mi][ni][r] + bias);
                } else {
                    const float bias = bv[n_in];
                    ushort4 pk;
                    pk.x = f2bf(acc[mi][ni][0] + bias);
                    pk.y = f2bf(acc[mi][ni][1] + bias);
                    pk.z = f2bf(acc[mi][ni][2] + bias);
                    pk.w = f2bf(acc[mi][ni][3] + bias);
                    // v stored transposed: [B,H,D,T], 4 consecutive t -> 8B store
                    *reinterpret_cast<ushort4*>(&vTws[((size_t)(b * NH + h) * HD + d) * 1024 + t]) = pk;
                }
            }
        }
    }
}

// ---------------- causal flash attention, 64 q-rows/block, 4 waves x 16 rows --
// Swapped QK^T: S^T = mfma(K, Q) so each lane owns one q-row (q = lane&15) and
// softmax reductions are in-lane + 2 cross-group shfl.
__global__ __launch_bounds__(256) void attn_kernel(
    const u16* __restrict__ qws, const u16* __restrict__ kws,
    const u16* __restrict__ vTws, u16* __restrict__ ctx)
{
    __shared__ __align__(16) u16 Ks[64][72];      // [kv][d + 8 pad]
    __shared__ __align__(16) u16 Vs[64][72];      // [d][kv + 8 pad]
    __shared__ __align__(16) u16 Ps[4][16][72];   // per-wave P^T: [q][kv + 8 pad]

    const int tid = threadIdx.x, lane = tid & 63, wid = tid >> 6;
    const int g = lane >> 4, c = lane & 15;
    const int bh = blockIdx.x;                 // 0..95
    const int qb = 15 - blockIdx.y;            // longest blocks dispatched first
    const int q0 = qb * 64;
    const u16* Qb = qws + (size_t)bh * 1024 * HD;
    const u16* Kb = kws + (size_t)bh * 1024 * HD;
    const u16* Vb = vTws + (size_t)bh * HD * 1024;

    // Q fragment (B-operand layout: col = c (q), k = kk*32 + g*8 + j)
    bf16x8 qf[2];
    const int qrow = q0 + wid * 16 + c;
    #pragma unroll
    for (int kk = 0; kk < 2; kk++)
        qf[kk] = *reinterpret_cast<const bf16x8*>(&Qb[(size_t)qrow * HD + kk * 32 + g * 8]);

    f32x4 o[4];
    #pragma unroll
    for (int df = 0; df < 4; df++) o[df] = (f32x4){0.f, 0.f, 0.f, 0.f};
    float m_run = -INFINITY, l_run = 0.f;

    const int ntiles = qb + 1;
    for (int it = 0; it < ntiles; ++it) {
        const int kv0 = it * 64;
        __syncthreads();
        #pragma unroll
        for (int rp = 0; rp < 2; ++rp) {
            int e = rp * 2048 + tid * 8;
            int row = e >> 6, col = e & 63;
            *reinterpret_cast<uint4*>(&Ks[row][col]) =
                *reinterpret_cast<const uint4*>(&Kb[(size_t)(kv0 + row) * HD + col]);
            *reinterpret_cast<uint4*>(&Vs[row][col]) =
                *reinterpret_cast<const uint4*>(&Vb[(size_t)row * 1024 + kv0 + col]);
        }
        __syncthreads();

        // S^T = K Q^T; output col = c = q, row = kv = cf*16 + g*4 + r
        float st[4][4];
        __builtin_amdgcn_s_setprio(1);
        #pragma unroll
        for (int cf = 0; cf < 4; cf++) {
            f32x4 sc = (f32x4){0.f, 0.f, 0.f, 0.f};
            #pragma unroll
            for (int kk = 0; kk < 2; kk++) {
                bf16x8 kb = *reinterpret_cast<const bf16x8*>(&Ks[cf * 16 + c][kk * 32 + g * 8]);
                sc = __builtin_amdgcn_mfma_f32_16x16x32_bf16(kb, qf[kk], sc, 0, 0, 0);
            }
            #pragma unroll
            for (int r = 0; r < 4; r++) st[cf][r] = sc[r];
        }
        __builtin_amdgcn_s_setprio(0);

        if (kv0 == q0) {   // diagonal tile: causal mask (local indices)
            const int q = wid * 16 + c;
            #pragma unroll
            for (int cf = 0; cf < 4; cf++)
                #pragma unroll
                for (int r = 0; r < 4; r++)
                    if (cf * 16 + g * 4 + r > q) st[cf][r] = -INFINITY;
        }

        // online softmax: lane owns q-row = c; in-lane reduce 16 + 2 shfl over g
        float tm = st[0][0];
        #pragma unroll
        for (int cf = 0; cf < 4; cf++)
            #pragma unroll
            for (int r = 0; r < 4; r++) tm = fmaxf(tm, st[cf][r]);
        tm = fmaxf(tm, __shfl_xor(tm, 16));
        tm = fmaxf(tm, __shfl_xor(tm, 32));
        const float mn = fmaxf(m_run, tm);
        const float corr = exp2f(m_run - mn);
        float rs = 0.f;
        #pragma unroll
        for (int cf = 0; cf < 4; cf++)
            #pragma unroll
            for (int r = 0; r < 4; r++) {
                const float p = exp2f(st[cf][r] - mn);
                st[cf][r] = p;
                rs += p;
            }
        rs += __shfl_xor(rs, 16);
        rs += __shfl_xor(rs, 32);
        l_run = l_run * corr + rs;
        m_run = mn;

        // O rows are q = g*4 + r -> fetch corr from lane (g*4+r)
        #pragma unroll
        for (int r = 0; r < 4; r++) {
            const float cr = __shfl(corr, g * 4 + r);
            #pragma unroll
            for (int df = 0; df < 4; df++) o[df][r] *= cr;
        }

        // pack P^T -> per-wave LDS in PV A-fragment order: Ps[q][kv]
        #pragma unroll
        for (int cf = 0; cf < 4; cf++) {
            ushort4 pk;
            pk.x = f2bf(st[cf][0]); pk.y = f2bf(st[cf][1]);
            pk.z = f2bf(st[cf][2]); pk.w = f2bf(st[cf][3]);
            *reinterpret_cast<ushort4*>(&Ps[wid][c][cf * 16 + g * 4]) = pk;
        }
        asm volatile("s_waitcnt lgkmcnt(0)" ::: "memory");
        __builtin_amdgcn_sched_barrier(0);
        bf16x8 pa[2];
        #pragma unroll
        for (int kk = 0; kk < 2; kk++)
            pa[kk] = *reinterpret_cast<const bf16x8*>(&Ps[wid][c][kk * 32 + g * 8]);

        // O += P @ V
        __builtin_amdgcn_s_setprio(1);
        #pragma unroll
        for (int df = 0; df < 4; df++) {
            #pragma unroll
            for (int kk = 0; kk < 2; kk++) {
                bf16x8 vb = *reinterpret_cast<const bf16x8*>(&Vs[df * 16 + c][kk * 32 + g * 8]);
                o[df] = __builtin_amdgcn_mfma_f32_16x16x32_bf16(pa[kk], vb, o[df], 0, 0, 0);
            }
        }
        __builtin_amdgcn_s_setprio(0);
    }

    // epilogue: ctx [B,T,E] bf16; l for row q=g*4+r lives in lane (g*4+r)
    const int b = bh / NH, h = bh % NH;
    float lb[4];
    #pragma unroll
    for (int r = 0; r < 4; r++) lb[r] = __shfl(l_run, g * 4 + r);
    #pragma unroll
    for (int df = 0; df < 4; df++) {
        #pragma unroll
        for (int r = 0; r < 4; r++) {
            const float val = o[df][r] / lb[r];
            const int t = q0 + wid * 16 + g * 4 + r;
            ctx[((size_t)(b * 1024 + t)) * EDIM + h * HD + df * 16 + c] = f2bf(val);
        }
    }
}

extern "C" void kernel_launch(void* const* d_in, const int* in_sizes, int n_in,
                              void* d_out, int out_size, void* d_ws, size_t ws_size,
                              hipStream_t stream) {
    const float* x  = (const float*)d_in[0];
    const float* Wq = (const float*)d_in[1];
    const float* bq = (const float*)d_in[2];
    const float* Wk = (const float*)d_in[3];
    const float* bk = (const float*)d_in[4];
    const float* Wv = (const float*)d_in[5];
    const float* bv = (const float*)d_in[6];
    const float* Wo = (const float*)d_in[7];
    const float* bo = (const float*)d_in[8];
    float* out = (float*)d_out;

    // workspace layout (all bf16 u16), total ~64.5 MB
    u16* xb  = (u16*)d_ws;
    u16* wb  = xb  + (size_t)MTOT * EDIM;          // 4 x [768][768]
    u16* qws = wb  + (size_t)4 * EDIM * EDIM;      // [B,H,T,D]
    u16* kws = qws + (size_t)MTOT * EDIM;          // [B,H,T,D]
    u16* vT  = kws + (size_t)MTOT * EDIM;          // [B,H,D,T]
    u16* ctx = vT  + (size_t)MTOT * EDIM;          // [B,T,E]

    cvt_kernel<<<(MTOT * EDIM / 8 + 255) / 256, 256, 0, stream>>>(x, xb, MTOT * EDIM / 8);
    cvt4_kernel<<<dim3(EDIM * EDIM / 8 / 256, 4), 256, 0, stream>>>(Wq, Wk, Wv, Wo, wb);

    gemm_bt<0><<<dim3(MTOT / 128, 18), 256, 0, stream>>>(xb, wb, bq, bk, bv, bo, qws, kws, vT, nullptr);
    attn_kernel<<<dim3(96, 16), 256, 0, stream>>>(qws, kws, vT, ctx);
    gemm_bt<1><<<dim3(MTOT / 128, 6), 256, 0, stream>>>(ctx, wb, bq, bk, bv, bo, nullptr, nullptr, nullptr, out);
}